// Round 12
// baseline (579.719 us; speedup 1.0000x reference)
//
#include <hip/hip_runtime.h>
#include <hip/hip_cooperative_groups.h>

namespace cg = cooperative_groups;

#define N_NODES 50000
#define DIM     128
#define E_EDGES 800000
#define ELLW    64        // ELL row stride; Poisson(16) in-degree, P(deg > 60) ~ 1e-18

typedef __attribute__((ext_vector_type(8))) short short8;
typedef __attribute__((ext_vector_type(4))) float f32x4;

__device__ __forceinline__ float bflo(unsigned int u){ return __uint_as_float(u << 16); }
__device__ __forceinline__ float bfhi(unsigned int u){ return __uint_as_float(u & 0xFFFF0000u); }
__device__ __forceinline__ unsigned int f2bf(float f){
  unsigned int u = __float_as_uint(f);
  return (u + 0x7FFFu + ((u >> 16) & 1u)) >> 16;
}
__device__ __forceinline__ unsigned int pack2(float a, float b){
  return f2bf(a) | (f2bf(b) << 16);
}

struct Params {
  const float* x; const int* edges;
  const float* lng0; const float* lnb0; const float* W0; const float* b0;
  const float* lng1; const float* lnb1; const float* W1; const float* b1;
  const float* lng2; const float* lnb2; const float* W2; const float* b2;
  int* cnt; int* epos; int2* ell; unsigned short* Wt;
  unsigned short* hn; unsigned short* yb; float* out;
};

// ---- gemm tile, M=64 (4 waves x 16 rows), bf16 A (round-9 low-reg variant) ----
__device__ __forceinline__ void gemm_tile(const unsigned short* __restrict__ A,
                                          const unsigned short* __restrict__ ldsb,
                                          unsigned short* __restrict__ Y,
                                          int base, int wave, int quad, int l15){
  int rbase = base + wave * 16;
  int rm = rbase + l15; if (rm > N_NODES - 1) rm = N_NODES - 1;
  short8 a[4];
  #pragma unroll
  for (int kk = 0; kk < 4; ++kk)
    a[kk] = *(const short8*)(A + (size_t)rm * 128 + kk * 32 + quad * 8);
  f32x4 acc[8];
  #pragma unroll
  for (int nt = 0; nt < 8; ++nt) acc[nt] = (f32x4){0.f, 0.f, 0.f, 0.f};
  #pragma unroll
  for (int kk = 0; kk < 4; ++kk)
    #pragma unroll
    for (int nt = 0; nt < 8; ++nt){
      short8 b = *(const short8*)&ldsb[(nt * 16 + l15) * 136 + kk * 32 + quad * 8];
      acc[nt] = __builtin_amdgcn_mfma_f32_16x16x32_bf16(a[kk], b, acc[nt], 0, 0, 0);
    }
  #pragma unroll
  for (int nt = 0; nt < 8; ++nt)
    #pragma unroll
    for (int r = 0; r < 4; ++r){
      int row = rbase + quad * 4 + r;
      if (row < N_NODES)
        Y[(size_t)row * 128 + nt * 16 + l15] = (unsigned short)f2bf(acc[nt][r]);
    }
}

// ---- gemm tile with fused LN+ReLU, fp32 X input (single row/wave, low-reg) ----
__device__ __forceinline__ void gemm_ln_tile(const float* __restrict__ X,
                                             const float* __restrict__ g,
                                             const float* __restrict__ bt,
                                             const unsigned short* __restrict__ ldsb,
                                             unsigned short* __restrict__ Y,
                                             int base, int wave, int quad, int l15){
  int rbase = base + wave * 16;
  int rm = rbase + l15; if (rm > N_NODES - 1) rm = N_NODES - 1;
  float v[4][8];
  float s = 0.f, ss = 0.f;
  #pragma unroll
  for (int kk = 0; kk < 4; ++kk){
    float4 xa = *(const float4*)(X + (size_t)rm * 128 + kk * 32 + quad * 8);
    float4 xb = *(const float4*)(X + (size_t)rm * 128 + kk * 32 + quad * 8 + 4);
    v[kk][0]=xa.x; v[kk][1]=xa.y; v[kk][2]=xa.z; v[kk][3]=xa.w;
    v[kk][4]=xb.x; v[kk][5]=xb.y; v[kk][6]=xb.z; v[kk][7]=xb.w;
    #pragma unroll
    for (int j = 0; j < 8; ++j){ s += v[kk][j]; ss += v[kk][j] * v[kk][j]; }
  }
  s += __shfl_xor(s, 16, 64); ss += __shfl_xor(ss, 16, 64);
  s += __shfl_xor(s, 32, 64); ss += __shfl_xor(ss, 32, 64);
  float mu = s * (1.0f/128.0f), var = ss * (1.0f/128.0f) - mu * mu;
  float rs = rsqrtf(var + 1e-5f);
  short8 a[4];
  #pragma unroll
  for (int kk = 0; kk < 4; ++kk){
    float4 ga = *(const float4*)(g  + kk * 32 + quad * 8);
    float4 gb = *(const float4*)(g  + kk * 32 + quad * 8 + 4);
    float4 ba = *(const float4*)(bt + kk * 32 + quad * 8);
    float4 bb = *(const float4*)(bt + kk * 32 + quad * 8 + 4);
    float gg[8]  = {ga.x,ga.y,ga.z,ga.w,gb.x,gb.y,gb.z,gb.w};
    float bbv[8] = {ba.x,ba.y,ba.z,ba.w,bb.x,bb.y,bb.z,bb.w};
    #pragma unroll
    for (int j = 0; j < 8; ++j){
      float h = fmaxf((v[kk][j] - mu) * rs * gg[j] + bbv[j], 0.0f);
      a[kk][j] = (short)f2bf(h);
    }
  }
  f32x4 acc[8];
  #pragma unroll
  for (int nt = 0; nt < 8; ++nt) acc[nt] = (f32x4){0.f, 0.f, 0.f, 0.f};
  #pragma unroll
  for (int kk = 0; kk < 4; ++kk)
    #pragma unroll
    for (int nt = 0; nt < 8; ++nt){
      short8 b = *(const short8*)&ldsb[(nt * 16 + l15) * 136 + kk * 32 + quad * 8];
      acc[nt] = __builtin_amdgcn_mfma_f32_16x16x32_bf16(a[kk], b, acc[nt], 0, 0, 0);
    }
  #pragma unroll
  for (int nt = 0; nt < 8; ++nt)
    #pragma unroll
    for (int r = 0; r < 4; ++r){
      int row = rbase + quad * 4 + r;
      if (row < N_NODES)
        Y[(size_t)row * 128 + nt * 16 + l15] = (unsigned short)f2bf(acc[nt][r]);
    }
}

// ---- agg phase: 4 nodes/wave, uint4 gathers (round-11 proven), grid-stride ----
template<bool HAS_RES, bool DO_LN>
__device__ __forceinline__ void agg_phase(const Params& P,
                                          const unsigned short* __restrict__ y,
                                          const float* __restrict__ bias,
                                          const float* __restrict__ res,
                                          float* __restrict__ outp,
                                          const float* __restrict__ lng,
                                          const float* __restrict__ lnb,
                                          unsigned short* __restrict__ hn_out,
                                          int GB){
  int tid = threadIdx.x, lane = tid & 63, wave = tid >> 6;
  int hl = lane & 15, selbase = lane & 48;
  const uint4* y4 = (const uint4*)y;
  for (int u = blockIdx.x; u < 3125; u += GB){
    int node = u * 16 + wave * 4 + (lane >> 4);   // 50000 exactly
    int deg = P.cnt[node];
    float di = rsqrtf((float)(deg + 1));
    float ws = di * di;

    const int2* row = P.ell + (size_t)node * ELLW;
    int2 e0 = row[hl], e1 = row[hl + 16], e2 = row[hl + 32], e3 = row[hl + 48];

    int J = deg;
    J = max(J, __shfl_xor(J, 16, 64));
    J = max(J, __shfl_xor(J, 32, 64));

    uint4 us = y4[(size_t)node * 16 + hl];
    float acc0 = ws * bflo(us.x), acc1 = ws * bfhi(us.x);
    float acc2 = ws * bflo(us.y), acc3 = ws * bfhi(us.y);
    float acc4 = ws * bflo(us.z), acc5 = ws * bfhi(us.z);
    float acc6 = ws * bflo(us.w), acc7 = ws * bfhi(us.w);

    auto block16 = [&](int2 ee, int base16){
      int rem = J - base16;
      if (rem <= 0) return;
      int nch = (min(rem, 16) + 3) >> 2;
      for (int c = 0; c < nch; ++c){
        int rb = c * 4;
        int sA = __shfl(ee.x, selbase | (rb + 0), 64);
        int sB = __shfl(ee.x, selbase | (rb + 1), 64);
        int sC = __shfl(ee.x, selbase | (rb + 2), 64);
        int sD = __shfl(ee.x, selbase | (rb + 3), 64);
        float wA = __uint_as_float((unsigned)__shfl(ee.y, selbase | (rb + 0), 64));
        float wB = __uint_as_float((unsigned)__shfl(ee.y, selbase | (rb + 1), 64));
        float wC = __uint_as_float((unsigned)__shfl(ee.y, selbase | (rb + 2), 64));
        float wD = __uint_as_float((unsigned)__shfl(ee.y, selbase | (rb + 3), 64));
        uint4 gA = y4[(size_t)sA * 16 + hl];
        uint4 gB = y4[(size_t)sB * 16 + hl];
        uint4 gC = y4[(size_t)sC * 16 + hl];
        uint4 gD = y4[(size_t)sD * 16 + hl];
        acc0 += wA*bflo(gA.x); acc1 += wA*bfhi(gA.x); acc2 += wA*bflo(gA.y); acc3 += wA*bfhi(gA.y);
        acc4 += wA*bflo(gA.z); acc5 += wA*bfhi(gA.z); acc6 += wA*bflo(gA.w); acc7 += wA*bfhi(gA.w);
        acc0 += wB*bflo(gB.x); acc1 += wB*bfhi(gB.x); acc2 += wB*bflo(gB.y); acc3 += wB*bfhi(gB.y);
        acc4 += wB*bflo(gB.z); acc5 += wB*bfhi(gB.z); acc6 += wB*bflo(gB.w); acc7 += wB*bfhi(gB.w);
        acc0 += wC*bflo(gC.x); acc1 += wC*bfhi(gC.x); acc2 += wC*bflo(gC.y); acc3 += wC*bfhi(gC.y);
        acc4 += wC*bflo(gC.z); acc5 += wC*bfhi(gC.z); acc6 += wC*bflo(gC.w); acc7 += wC*bfhi(gC.w);
        acc0 += wD*bflo(gD.x); acc1 += wD*bfhi(gD.x); acc2 += wD*bflo(gD.y); acc3 += wD*bfhi(gD.y);
        acc4 += wD*bflo(gD.z); acc5 += wD*bfhi(gD.z); acc6 += wD*bflo(gD.w); acc7 += wD*bfhi(gD.w);
      }
    };
    block16(e0, 0); block16(e1, 16); block16(e2, 32); block16(e3, 48);

    float4 ubA = ((const float4*)bias)[hl * 2];
    float4 ubB = ((const float4*)bias)[hl * 2 + 1];
    acc0 += ubA.x; acc1 += ubA.y; acc2 += ubA.z; acc3 += ubA.w;
    acc4 += ubB.x; acc5 += ubB.y; acc6 += ubB.z; acc7 += ubB.w;
    if (HAS_RES){
      float4 urA = ((const float4*)res)[(size_t)node * 32 + hl * 2];
      float4 urB = ((const float4*)res)[(size_t)node * 32 + hl * 2 + 1];
      acc0 += urA.x; acc1 += urA.y; acc2 += urA.z; acc3 += urA.w;
      acc4 += urB.x; acc5 += urB.y; acc6 += urB.z; acc7 += urB.w;
    }
    if (outp){
      float4 oA; oA.x = acc0; oA.y = acc1; oA.z = acc2; oA.w = acc3;
      float4 oB; oB.x = acc4; oB.y = acc5; oB.z = acc6; oB.w = acc7;
      ((float4*)outp)[(size_t)node * 32 + hl * 2]     = oA;
      ((float4*)outp)[(size_t)node * 32 + hl * 2 + 1] = oB;
    }
    if (DO_LN){
      float s  = acc0 + acc1 + acc2 + acc3 + acc4 + acc5 + acc6 + acc7;
      float ss = acc0*acc0 + acc1*acc1 + acc2*acc2 + acc3*acc3
               + acc4*acc4 + acc5*acc5 + acc6*acc6 + acc7*acc7;
      #pragma unroll
      for (int d = 8; d >= 1; d >>= 1){ s += __shfl_xor(s, d, 64); ss += __shfl_xor(ss, d, 64); }
      float mu  = s * (1.0f / 128.0f);
      float var = ss * (1.0f / 128.0f) - mu * mu;
      float rs  = rsqrtf(var + 1e-5f);
      float4 ugA = ((const float4*)lng)[hl * 2];
      float4 ugB = ((const float4*)lng)[hl * 2 + 1];
      float4 ubbA = ((const float4*)lnb)[hl * 2];
      float4 ubbB = ((const float4*)lnb)[hl * 2 + 1];
      float h0 = fmaxf((acc0 - mu) * rs * ugA.x + ubbA.x, 0.0f);
      float h1 = fmaxf((acc1 - mu) * rs * ugA.y + ubbA.y, 0.0f);
      float h2 = fmaxf((acc2 - mu) * rs * ugA.z + ubbA.z, 0.0f);
      float h3 = fmaxf((acc3 - mu) * rs * ugA.w + ubbA.w, 0.0f);
      float h4 = fmaxf((acc4 - mu) * rs * ugB.x + ubbB.x, 0.0f);
      float h5 = fmaxf((acc5 - mu) * rs * ugB.y + ubbB.y, 0.0f);
      float h6 = fmaxf((acc6 - mu) * rs * ugB.z + ubbB.z, 0.0f);
      float h7 = fmaxf((acc7 - mu) * rs * ugB.w + ubbB.w, 0.0f);
      uint4 ho;
      ho.x = pack2(h0, h1); ho.y = pack2(h2, h3);
      ho.z = pack2(h4, h5); ho.w = pack2(h6, h7);
      ((uint4*)hn_out)[(size_t)node * 16 + hl] = ho;
    }
  }
}

// ---------------- the single cooperative kernel (NO min-waves bound!) ----------------
// Round 9/10 failure root cause: __launch_bounds__(256,4) capped unified regs at 128
// -> compiler split 64 VGPR + 64 AGPR -> gather loop spilled to scratch every chunk
// (WRITE_SIZE +200MB, VALUBusy 4%). Default bounds let the allocator take ~110 regs.

__global__ __launch_bounds__(256) void mono_kernel(Params P){
  cg::grid_group grid = cg::this_grid();
  __shared__ unsigned short ldsb[128 * 136];   // 34.8 KB -> <=4 blocks/CU
  const int GB   = gridDim.x;
  const int tid  = threadIdx.x;
  const int wave = tid >> 6, lane = tid & 63;
  const int quad = lane >> 4, l15 = lane & 15;

  // ---- P0: zero cnt ----
  for (int u = blockIdx.x; u < 196; u += GB){
    int i = u * 256 + tid;
    if (i < N_NODES) P.cnt[i] = 0;
  }
  grid.sync();

  // ---- P1: count (atomics + epos) || cvt W0..W2 -> bf16 Wt^T ----
  {
    const int NU_CNT = 3125, NU_CVT = 192;
    for (int u = blockIdx.x; u < NU_CNT + NU_CVT; u += GB){
      if (u < NU_CNT){
        int e = u * 256 + tid;
        if (e < E_EDGES) P.epos[e] = atomicAdd(&P.cnt[P.edges[E_EDGES + e]], 1);
      } else {
        int idx = (u - NU_CNT) * 256 + tid;        // < 49152
        int w = idx >> 14, r = idx & 16383;
        const float* W = (w == 0) ? P.W0 : (w == 1) ? P.W1 : P.W2;
        P.Wt[w * 16384 + (r & 127) * 128 + (r >> 7)] = (unsigned short)f2bf(W[r]);
      }
    }
  }
  grid.sync();

  // ---- P2: fill ELL || pad ELL (group-of-4 J) || gemm_ln0 ----
  {
    #pragma unroll
    for (int it = 0; it < 8; ++it){
      int c = tid + it * 256;
      int n = c >> 4, kc = c & 15;
      *(short8*)&ldsb[n * 136 + kc * 8] = *(const short8*)(P.Wt + n * 128 + kc * 8);
    }
    __syncthreads();
    const int NU_FILL = 3125, NU_PAD = 196, NU_G = 782;
    for (int u = blockIdx.x; u < NU_FILL + NU_PAD + NU_G; u += GB){
      if (u < NU_FILL){
        int e = u * 256 + tid;
        if (e < E_EDGES){
          int s = P.edges[e], d = P.edges[E_EDGES + e];
          int pos = P.epos[e];
          if (pos < ELLW){
            float w = rsqrtf((float)(P.cnt[s] + 1)) * rsqrtf((float)(P.cnt[d] + 1));
            int2 pk; pk.x = s; pk.y = __float_as_int(w);
            P.ell[(size_t)d * ELLW + pos] = pk;
          }
        }
      } else if (u < NU_FILL + NU_PAD){
        int i = (u - NU_FILL) * 256 + tid;
        if (i < N_NODES){
          int deg = P.cnt[i];
          int g4 = i & ~3;   // agg wave covers nodes [g4, g4+4) with shared J
          int J = max(max(P.cnt[g4], P.cnt[g4 + 1]), max(P.cnt[g4 + 2], P.cnt[g4 + 3]));
          int J4 = min(ELLW, (J + 3) & ~3);
          int2 z; z.x = 0; z.y = 0;
          for (int pp = min(deg, J4); pp < J4; ++pp)
            P.ell[(size_t)i * ELLW + pp] = z;
        }
      } else {
        gemm_ln_tile(P.x, P.lng0, P.lnb0, ldsb, P.yb,
                     (u - NU_FILL - NU_PAD) * 64, wave, quad, l15);
      }
    }
  }
  grid.sync();

  // ---- P3: agg0 (res=x, out->d_out, fused LN1 -> hn) ----
  agg_phase<true, true>(P, P.yb, P.b0, P.x, P.out, P.lng1, P.lnb1, P.hn, GB);
  grid.sync();

  // ---- P4: gemm1 (hn -> yb) ----
  {
    #pragma unroll
    for (int it = 0; it < 8; ++it){
      int c = tid + it * 256;
      int n = c >> 4, kc = c & 15;
      *(short8*)&ldsb[n * 136 + kc * 8] = *(const short8*)(P.Wt + 16384 + n * 128 + kc * 8);
    }
    __syncthreads();
    for (int u = blockIdx.x; u < 782; u += GB)
      gemm_tile(P.hn, ldsb, P.yb, u * 64, wave, quad, l15);
  }
  grid.sync();

  // ---- P5: agg1 (no res, no out, fused LN2 -> hn) ----
  agg_phase<false, true>(P, P.yb, P.b1, nullptr, nullptr, P.lng2, P.lnb2, P.hn, GB);
  grid.sync();

  // ---- P6: gemm2 (hn -> yb) ----
  {
    #pragma unroll
    for (int it = 0; it < 8; ++it){
      int c = tid + it * 256;
      int n = c >> 4, kc = c & 15;
      *(short8*)&ldsb[n * 136 + kc * 8] = *(const short8*)(P.Wt + 32768 + n * 128 + kc * 8);
    }
    __syncthreads();
    for (int u = blockIdx.x; u < 782; u += GB)
      gemm_tile(P.hn, ldsb, P.yb, u * 64, wave, quad, l15);
  }
  grid.sync();

  // ---- P7: agg2 (res=x1 from d_out, out->d_out, no LN) ----
  agg_phase<true, false>(P, P.yb, P.b2, P.out, P.out, nullptr, nullptr, nullptr, GB);
}

// ---------------- launch ----------------

extern "C" void kernel_launch(void* const* d_in, const int* in_sizes, int n_in,
                              void* d_out, int out_size, void* d_ws, size_t ws_size,
                              hipStream_t stream){
  Params P;
  P.x    = (const float*)d_in[0];
  P.edges= (const int*)d_in[1];
  P.lng0 = (const float*)d_in[2];  P.lnb0 = (const float*)d_in[3];
  P.W0   = (const float*)d_in[4];  P.b0   = (const float*)d_in[5];
  P.lng1 = (const float*)d_in[6];  P.lnb1 = (const float*)d_in[7];
  P.W1   = (const float*)d_in[8];  P.b1   = (const float*)d_in[9];
  P.lng2 = (const float*)d_in[10]; P.lnb2 = (const float*)d_in[11];
  P.W2   = (const float*)d_in[12]; P.b2   = (const float*)d_in[13];

  char* p = (char*)d_ws;
  auto carve = [&](size_t bytes) -> void* {
    void* r = (void*)p;
    p += (bytes + 255) & ~(size_t)255;
    return r;
  };
  P.cnt  = (int*)  carve(N_NODES * 4);
  P.epos = (int*)  carve((size_t)E_EDGES * 4);
  P.ell  = (int2*) carve((size_t)N_NODES * ELLW * 8);   // 25.6 MB; pad phase covers reads
  P.Wt   = (unsigned short*)carve(3 * 128 * 128 * 2);
  P.hn   = (unsigned short*)carve((size_t)N_NODES * 128 * 2);
  P.yb   = (unsigned short*)carve((size_t)N_NODES * 128 * 2);
  P.out  = (float*)d_out;   // doubles as x1 storage (layer-0 residual output)

  // Grid sized to guaranteed co-residency for the cooperative launch.
  int maxb = 0;
  hipError_t oe = hipOccupancyMaxActiveBlocksPerMultiprocessor(&maxb, mono_kernel, 256, 0);
  int ncu = 256;
  int dev = 0;
  hipGetDevice(&dev);
  hipDeviceGetAttribute(&ncu, hipDeviceAttributeMultiprocessorCount, dev);
  int GB = (oe == hipSuccess && maxb > 0) ? maxb * ncu : 2 * ncu;
  if (GB > 4103) GB = 4103;   // largest phase has 4103 units

  void* args[] = { (void*)&P };
  hipLaunchCooperativeKernel(mono_kernel, dim3(GB), dim3(256), args, 0, stream);
}

// Round 13
// 355.385 us; speedup vs baseline: 1.6312x; 1.6312x over previous
//
#include <hip/hip_runtime.h>

#define N_NODES 50000
#define DIM     128
#define E_EDGES 800000
#define ELLW    64        // ELL row stride; Poisson(16) in-degree, P(deg > 60) ~ 1e-18

typedef __attribute__((ext_vector_type(8))) short short8;
typedef __attribute__((ext_vector_type(4))) float f32x4;

__device__ __forceinline__ float bflo(unsigned int u){ return __uint_as_float(u << 16); }
__device__ __forceinline__ float bfhi(unsigned int u){ return __uint_as_float(u & 0xFFFF0000u); }
__device__ __forceinline__ unsigned int f2bf(float f){
  unsigned int u = __float_as_uint(f);
  return (u + 0x7FFFu + ((u >> 16) & 1u)) >> 16;
}

// ---------------- count: atomics + per-edge slot record ----------------

__global__ __launch_bounds__(256) void count_kernel(const int* __restrict__ edges,
                                                    int* __restrict__ cnt,
                                                    int* __restrict__ epos){
  int e = blockIdx.x * 256 + threadIdx.x;
  if (e < E_EDGES) epos[e] = atomicAdd(&cnt[edges[E_EDGES + e]], 1);
}

// ---------------- prep: fill ELL | pad ELL (group-of-8 J) | cvt W (block ranges) ----
// blocks [0,3125): fill; [3125,3321): pad; [3321,3513): cvtw.

__global__ __launch_bounds__(256) void prep_kernel(const int* __restrict__ edges,
                                                   const int* __restrict__ epos,
                                                   const int* __restrict__ cnt,
                                                   int2* __restrict__ ell,
                                                   const float* __restrict__ W0,
                                                   const float* __restrict__ W1,
                                                   const float* __restrict__ W2,
                                                   unsigned short* __restrict__ Wt){
  int u = blockIdx.x, tid = threadIdx.x;
  if (u < 3125){
    int e = u * 256 + tid;
    if (e < E_EDGES){
      int s = edges[e];
      int d = edges[E_EDGES + e];
      int pos = epos[e];
      if (pos < ELLW){
        float w = rsqrtf((float)(cnt[s] + 1)) * rsqrtf((float)(cnt[d] + 1));
        int2 pk; pk.x = s; pk.y = __float_as_int(w);
        ell[(size_t)d * ELLW + pos] = pk;
      }
    }
  } else if (u < 3125 + 196){
    int i = (u - 3125) * 256 + tid;
    if (i < N_NODES){
      int deg = cnt[i];
      int g8 = i & ~7;   // agg wave covers nodes [g8, g8+8) with shared J (50000 % 8 == 0)
      int J = 0;
      #pragma unroll
      for (int j = 0; j < 8; ++j) J = max(J, cnt[g8 + j]);
      int J4 = min(ELLW, (J + 3) & ~3);
      int2 z; z.x = 0; z.y = 0;
      for (int pp = min(deg, J4); pp < J4; ++pp)
        ell[(size_t)i * ELLW + pp] = z;
    }
  } else {
    int idx = (u - 3321) * 256 + tid;   // < 49152
    int w = idx >> 14, r = idx & 16383;
    const float* W = (w == 0) ? W0 : (w == 1) ? W1 : W2;
    Wt[w * 16384 + (r & 127) * 128 + (r >> 7)] = (unsigned short)f2bf(W[r]);
  }
}

// ---------------- GEMM with fused LN+ReLU on fp32 input (all 3 layers) ----------------

__global__ __launch_bounds__(256) void gemm_ln_mfma(const float* __restrict__ X,
                                                    const float* __restrict__ g,
                                                    const float* __restrict__ bt,
                                                    const unsigned short* __restrict__ Wt,
                                                    unsigned short* __restrict__ Y){
  __shared__ unsigned short ldsb[128 * 136];
  int tid = threadIdx.x;
  #pragma unroll
  for (int it = 0; it < 8; ++it){
    int c  = tid + it * 256;
    int n  = c >> 4, kc = c & 15;
    *(short8*)&ldsb[n * 136 + kc * 8] = *(const short8*)(Wt + n * 128 + kc * 8);
  }
  int wave = tid >> 6, lane = tid & 63, quad = lane >> 4, l15 = lane & 15;
  int rowbase = blockIdx.x * 128 + wave * 32;
  int rm0 = rowbase + l15;      if (rm0 > N_NODES - 1) rm0 = N_NODES - 1;
  int rm1 = rowbase + 16 + l15; if (rm1 > N_NODES - 1) rm1 = N_NODES - 1;

  float v0[4][8], v1[4][8];
  float s0 = 0.f, ss0 = 0.f, s1 = 0.f, ss1 = 0.f;
  #pragma unroll
  for (int kk = 0; kk < 4; ++kk){
    float4 xa = *(const float4*)(X + (size_t)rm0 * 128 + kk * 32 + quad * 8);
    float4 xb = *(const float4*)(X + (size_t)rm0 * 128 + kk * 32 + quad * 8 + 4);
    float4 ya = *(const float4*)(X + (size_t)rm1 * 128 + kk * 32 + quad * 8);
    float4 yb_ = *(const float4*)(X + (size_t)rm1 * 128 + kk * 32 + quad * 8 + 4);
    v0[kk][0]=xa.x; v0[kk][1]=xa.y; v0[kk][2]=xa.z; v0[kk][3]=xa.w;
    v0[kk][4]=xb.x; v0[kk][5]=xb.y; v0[kk][6]=xb.z; v0[kk][7]=xb.w;
    v1[kk][0]=ya.x; v1[kk][1]=ya.y; v1[kk][2]=ya.z; v1[kk][3]=ya.w;
    v1[kk][4]=yb_.x; v1[kk][5]=yb_.y; v1[kk][6]=yb_.z; v1[kk][7]=yb_.w;
    #pragma unroll
    for (int j = 0; j < 8; ++j){
      s0 += v0[kk][j]; ss0 += v0[kk][j] * v0[kk][j];
      s1 += v1[kk][j]; ss1 += v1[kk][j] * v1[kk][j];
    }
  }
  s0 += __shfl_xor(s0, 16, 64); ss0 += __shfl_xor(ss0, 16, 64);
  s0 += __shfl_xor(s0, 32, 64); ss0 += __shfl_xor(ss0, 32, 64);
  s1 += __shfl_xor(s1, 16, 64); ss1 += __shfl_xor(ss1, 16, 64);
  s1 += __shfl_xor(s1, 32, 64); ss1 += __shfl_xor(ss1, 32, 64);
  float mu0 = s0 * (1.0f/128.0f), var0 = ss0 * (1.0f/128.0f) - mu0*mu0;
  float mu1 = s1 * (1.0f/128.0f), var1 = ss1 * (1.0f/128.0f) - mu1*mu1;
  float rs0 = rsqrtf(var0 + 1e-5f), rs1 = rsqrtf(var1 + 1e-5f);

  short8 a0[4], a1[4];
  #pragma unroll
  for (int kk = 0; kk < 4; ++kk){
    float4 ga = *(const float4*)(g  + kk * 32 + quad * 8);
    float4 gb = *(const float4*)(g  + kk * 32 + quad * 8 + 4);
    float4 ba = *(const float4*)(bt + kk * 32 + quad * 8);
    float4 bb = *(const float4*)(bt + kk * 32 + quad * 8 + 4);
    float gg[8] = {ga.x,ga.y,ga.z,ga.w,gb.x,gb.y,gb.z,gb.w};
    float bbv[8] = {ba.x,ba.y,ba.z,ba.w,bb.x,bb.y,bb.z,bb.w};
    #pragma unroll
    for (int j = 0; j < 8; ++j){
      float h0 = fmaxf((v0[kk][j] - mu0) * rs0 * gg[j] + bbv[j], 0.0f);
      float h1 = fmaxf((v1[kk][j] - mu1) * rs1 * gg[j] + bbv[j], 0.0f);
      a0[kk][j] = (short)f2bf(h0);
      a1[kk][j] = (short)f2bf(h1);
    }
  }

  f32x4 acc[2][8];
  #pragma unroll
  for (int mt = 0; mt < 2; ++mt)
    #pragma unroll
    for (int nt = 0; nt < 8; ++nt) acc[mt][nt] = (f32x4){0.f, 0.f, 0.f, 0.f};
  __syncthreads();
  #pragma unroll
  for (int kk = 0; kk < 4; ++kk){
    #pragma unroll
    for (int nt = 0; nt < 8; ++nt){
      short8 b = *(const short8*)&ldsb[(nt * 16 + l15) * 136 + kk * 32 + quad * 8];
      acc[0][nt] = __builtin_amdgcn_mfma_f32_16x16x32_bf16(a0[kk], b, acc[0][nt], 0, 0, 0);
      acc[1][nt] = __builtin_amdgcn_mfma_f32_16x16x32_bf16(a1[kk], b, acc[1][nt], 0, 0, 0);
    }
  }
  #pragma unroll
  for (int mt = 0; mt < 2; ++mt)
    #pragma unroll
    for (int nt = 0; nt < 8; ++nt)
      #pragma unroll
      for (int r = 0; r < 4; ++r){
        int row = rowbase + mt * 16 + quad * 4 + r;
        if (row < N_NODES)
          Y[(size_t)row * 128 + nt * 16 + l15] = (unsigned short)f2bf(acc[mt][nt][r]);
      }
}

// ---------------- Aggregate, XCD-SLICED: no LN, fp32 out ----------------
// Slice s = blockIdx&3 covers features [s*32, s*32+32) = 64 B. With blockIdx%8 -> XCD,
// XCD k only touches slice k%4 of y (3.2 MB, L2-resident). 8 nodes/wave x 8 lanes x uint2;
// one gather instruction = 8 edges x 64 B. ELL row in 8 int2 regs, (src,w) via __shfl.
// Pads (src=0,w=0) cover to the group-of-8 J 4-boundary.

template<bool HAS_RES>
__global__ __launch_bounds__(256) void agg_kernel(const unsigned short* __restrict__ y,
                                                  const int* __restrict__ cnt,
                                                  const int2* __restrict__ ell,
                                                  const float* __restrict__ bias,
                                                  const float* __restrict__ res,
                                                  float* __restrict__ outp){
  int s   = blockIdx.x & 3;
  int g   = blockIdx.x >> 2;
  int tid = threadIdx.x, lane = tid & 63, wave = tid >> 6;
  int hl  = lane & 7;
  int node = g * 32 + wave * 8 + (lane >> 3);
  bool valid = node < N_NODES;
  int nc = valid ? node : (N_NODES - 1);

  int deg = cnt[nc];
  float di = rsqrtf((float)(deg + 1));
  float ws = di * di;

  // ELL preload: reg k holds entry hl + 8k of this node's row
  const int2* row = ell + (size_t)nc * ELLW;
  int2 e0 = row[hl],      e1 = row[hl + 8],  e2 = row[hl + 16], e3 = row[hl + 24];
  int2 e4 = row[hl + 32], e5 = row[hl + 40], e6 = row[hl + 48], e7 = row[hl + 56];

  int J = valid ? deg : 0;
  J = max(J, __shfl_xor(J, 8, 64));
  J = max(J, __shfl_xor(J, 16, 64));
  J = max(J, __shfl_xor(J, 32, 64));

  const uint2* y2 = (const uint2*)y;           // y row = 32 uint2
  size_t sb = (size_t)s * 8 + hl;              // slice offset within a row
  uint2 us = y2[(size_t)nc * 32 + sb];
  float a0 = ws * bflo(us.x), a1 = ws * bfhi(us.x);
  float a2 = ws * bflo(us.y), a3 = ws * bfhi(us.y);

  int selbase = lane & 56;
  auto block8 = [&](int2 ee, int base8){
    int rem = J - base8;
    if (rem <= 0) return;
    int jn = (min(rem, 8) + 3) & ~3;           // wave-uniform, pads cover to 4-boundary
    for (int j = 0; j < jn; j += 4){
      int sA = __shfl(ee.x, selbase | (j + 0), 64);
      int sB = __shfl(ee.x, selbase | (j + 1), 64);
      int sC = __shfl(ee.x, selbase | (j + 2), 64);
      int sD = __shfl(ee.x, selbase | (j + 3), 64);
      float wA = __uint_as_float((unsigned)__shfl(ee.y, selbase | (j + 0), 64));
      float wB = __uint_as_float((unsigned)__shfl(ee.y, selbase | (j + 1), 64));
      float wC = __uint_as_float((unsigned)__shfl(ee.y, selbase | (j + 2), 64));
      float wD = __uint_as_float((unsigned)__shfl(ee.y, selbase | (j + 3), 64));
      uint2 gA = y2[(size_t)sA * 32 + sb];
      uint2 gB = y2[(size_t)sB * 32 + sb];
      uint2 gC = y2[(size_t)sC * 32 + sb];
      uint2 gD = y2[(size_t)sD * 32 + sb];
      a0 += wA*bflo(gA.x); a1 += wA*bfhi(gA.x); a2 += wA*bflo(gA.y); a3 += wA*bfhi(gA.y);
      a0 += wB*bflo(gB.x); a1 += wB*bfhi(gB.x); a2 += wB*bflo(gB.y); a3 += wB*bfhi(gB.y);
      a0 += wC*bflo(gC.x); a1 += wC*bfhi(gC.x); a2 += wC*bflo(gC.y); a3 += wC*bfhi(gC.y);
      a0 += wD*bflo(gD.x); a1 += wD*bfhi(gD.x); a2 += wD*bflo(gD.y); a3 += wD*bfhi(gD.y);
    }
  };
  block8(e0, 0);  block8(e1, 8);  block8(e2, 16); block8(e3, 24);
  block8(e4, 32); block8(e5, 40); block8(e6, 48); block8(e7, 56);

  float4 ub = ((const float4*)bias)[sb];
  a0 += ub.x; a1 += ub.y; a2 += ub.z; a3 += ub.w;
  if (HAS_RES){
    float4 ur = ((const float4*)res)[(size_t)nc * 32 + sb];
    a0 += ur.x; a1 += ur.y; a2 += ur.z; a3 += ur.w;
  }
  if (valid){
    float4 o; o.x = a0; o.y = a1; o.z = a2; o.w = a3;
    ((float4*)outp)[(size_t)node * 32 + sb] = o;
  }
}

// ---------------- launch ----------------

extern "C" void kernel_launch(void* const* d_in, const int* in_sizes, int n_in,
                              void* d_out, int out_size, void* d_ws, size_t ws_size,
                              hipStream_t stream){
  const float* x    = (const float*)d_in[0];
  const int*   edges= (const int*)d_in[1];
  const float* lng0 = (const float*)d_in[2];
  const float* lnb0 = (const float*)d_in[3];
  const float* W0   = (const float*)d_in[4];
  const float* b0   = (const float*)d_in[5];
  const float* lng1 = (const float*)d_in[6];
  const float* lnb1 = (const float*)d_in[7];
  const float* W1   = (const float*)d_in[8];
  const float* b1   = (const float*)d_in[9];
  const float* lng2 = (const float*)d_in[10];
  const float* lnb2 = (const float*)d_in[11];
  const float* W2   = (const float*)d_in[12];
  const float* b2   = (const float*)d_in[13];

  char* p = (char*)d_ws;
  auto carve = [&](size_t bytes) -> void* {
    void* r = (void*)p;
    p += (bytes + 255) & ~(size_t)255;
    return r;
  };
  int*   cnt   = (int*)  carve(N_NODES * 4);
  int*   epos  = (int*)  carve((size_t)E_EDGES * 4);
  int2*  ell   = (int2*) carve((size_t)N_NODES * ELLW * 8);   // 25.6 MB; pad phase covers reads
  unsigned short* Wt  = (unsigned short*)carve(3 * 128 * 128 * 2);
  unsigned short* yb  = (unsigned short*)carve((size_t)N_NODES * 128 * 2);
  float*          h2p = (float*)carve((size_t)N_NODES * 128 * 4);   // layer-1 pre-LN output
  float* out = (float*)d_out;   // x1 storage (layer-0 residual output), then final out

  hipMemsetAsync(cnt, 0, N_NODES * 4, stream);   // 200 KB only

  count_kernel<<<(E_EDGES + 255) / 256, 256, 0, stream>>>(edges, cnt, epos);
  prep_kernel<<<3513, 256, 0, stream>>>(edges, epos, cnt, ell, W0, W1, W2, Wt);

  const int GEMM_GRID = (N_NODES + 127) / 128;      // 391
  const int AGG_GRID  = ((N_NODES + 31) / 32) * 4;  // 1563 node-groups x 4 slices = 6252

  // layer 0: y0 = relu(LN0(x))@W0 ; x1 = agg(y0)+b0+x -> d_out (fp32, sliced)
  gemm_ln_mfma<<<GEMM_GRID, 256, 0, stream>>>(x, lng0, lnb0, Wt, yb);
  agg_kernel<true><<<AGG_GRID, 256, 0, stream>>>(yb, cnt, ell, b0, x, out);
  // layer 1: y1 = relu(LN1(x1))@W1 ; h2p = agg(y1)+b1 (fp32, sliced)
  gemm_ln_mfma<<<GEMM_GRID, 256, 0, stream>>>(out, lng1, lnb1, Wt + 16384, yb);
  agg_kernel<false><<<AGG_GRID, 256, 0, stream>>>(yb, cnt, ell, b1, nullptr, h2p);
  // layer 2: y2 = relu(LN2(h2p))@W2 ; out = agg(y2)+b2+x1 (x1 read from d_out, in place)
  gemm_ln_mfma<<<GEMM_GRID, 256, 0, stream>>>(h2p, lng2, lnb2, Wt + 32768, yb);
  agg_kernel<true><<<AGG_GRID, 256, 0, stream>>>(yb, cnt, ell, b2, out, out);
}

// Round 14
// 289.039 us; speedup vs baseline: 2.0057x; 1.2295x over previous
//
#include <hip/hip_runtime.h>

#define N_NODES 50000
#define DIM     128
#define E_EDGES 800000
#define ELLW    64        // ELL row stride; Poisson(16) in-degree, P(deg > 60) ~ 1e-18

typedef __attribute__((ext_vector_type(8))) short short8;
typedef __attribute__((ext_vector_type(4))) float f32x4;

__device__ __forceinline__ float bflo(unsigned int u){ return __uint_as_float(u << 16); }
__device__ __forceinline__ float bfhi(unsigned int u){ return __uint_as_float(u & 0xFFFF0000u); }
__device__ __forceinline__ unsigned int f2bf(float f){
  unsigned int u = __float_as_uint(f);
  return (u + 0x7FFFu + ((u >> 16) & 1u)) >> 16;
}
__device__ __forceinline__ unsigned int pack2(float a, float b){
  return f2bf(a) | (f2bf(b) << 16);
}

// ---------------- count: atomics + per-edge slot record ----------------

__global__ __launch_bounds__(256) void count_kernel(const int* __restrict__ edges,
                                                    int* __restrict__ cnt,
                                                    int* __restrict__ epos){
  int e = blockIdx.x * 256 + threadIdx.x;
  if (e < E_EDGES) epos[e] = atomicAdd(&cnt[edges[E_EDGES + e]], 1);
}

// ---------------- prep: fill ELL | pad ELL | cvt W -> bf16 Wt^T (block ranges) ------
// ELL entry = 4 B: lo16 = src node id (N<65536), hi16 = bf16 edge weight.
// blocks [0,3125): fill; [3125,3321): pad; [3321,3513): cvtw.

__global__ __launch_bounds__(256) void prep_kernel(const int* __restrict__ edges,
                                                   const int* __restrict__ epos,
                                                   const int* __restrict__ cnt,
                                                   unsigned int* __restrict__ ell,
                                                   const float* __restrict__ W0,
                                                   const float* __restrict__ W1,
                                                   const float* __restrict__ W2,
                                                   unsigned short* __restrict__ Wt){
  int u = blockIdx.x, tid = threadIdx.x;
  if (u < 3125){
    int e = u * 256 + tid;
    if (e < E_EDGES){
      int s = edges[e];
      int d = edges[E_EDGES + e];
      int pos = epos[e];
      if (pos < ELLW){
        float w = rsqrtf((float)(cnt[s] + 1)) * rsqrtf((float)(cnt[d] + 1));
        ell[(size_t)d * ELLW + pos] = (unsigned)s | (f2bf(w) << 16);
      }
    }
  } else if (u < 3125 + 196){
    int i = (u - 3125) * 256 + tid;
    if (i < N_NODES){
      int deg = cnt[i];
      int g4 = i & ~3;   // agg wave covers nodes [g4, g4+4) with shared J
      int J = max(max(cnt[g4], cnt[g4 + 1]), max(cnt[g4 + 2], cnt[g4 + 3]));
      int J4 = min(ELLW, (J + 3) & ~3);
      for (int pp = min(deg, J4); pp < J4; ++pp)
        ell[(size_t)i * ELLW + pp] = 0u;        // src=0, w=+0.0bf16
    }
  } else {
    int idx = (u - 3321) * 256 + tid;   // < 49152
    int w = idx >> 14, r = idx & 16383;
    const float* W = (w == 0) ? W0 : (w == 1) ? W1 : W2;
    Wt[w * 16384 + (r & 127) * 128 + (r >> 7)] = (unsigned short)f2bf(W[r]);
  }
}

// ---------------- GEMM with fused LN+ReLU on fp32 input (layer 0) ----------------

__global__ __launch_bounds__(256) void gemm_ln_mfma(const float* __restrict__ X,
                                                    const float* __restrict__ g,
                                                    const float* __restrict__ bt,
                                                    const unsigned short* __restrict__ Wt,
                                                    unsigned short* __restrict__ Y){
  __shared__ unsigned short ldsb[128 * 136];
  int tid = threadIdx.x;
  #pragma unroll
  for (int it = 0; it < 8; ++it){
    int c  = tid + it * 256;
    int n  = c >> 4, kc = c & 15;
    *(short8*)&ldsb[n * 136 + kc * 8] = *(const short8*)(Wt + n * 128 + kc * 8);
  }
  int wave = tid >> 6, lane = tid & 63, quad = lane >> 4, l15 = lane & 15;
  int rowbase = blockIdx.x * 128 + wave * 32;
  int rm0 = rowbase + l15;      if (rm0 > N_NODES - 1) rm0 = N_NODES - 1;
  int rm1 = rowbase + 16 + l15; if (rm1 > N_NODES - 1) rm1 = N_NODES - 1;

  float v0[4][8], v1[4][8];
  float s0 = 0.f, ss0 = 0.f, s1 = 0.f, ss1 = 0.f;
  #pragma unroll
  for (int kk = 0; kk < 4; ++kk){
    float4 xa = *(const float4*)(X + (size_t)rm0 * 128 + kk * 32 + quad * 8);
    float4 xb = *(const float4*)(X + (size_t)rm0 * 128 + kk * 32 + quad * 8 + 4);
    float4 ya = *(const float4*)(X + (size_t)rm1 * 128 + kk * 32 + quad * 8);
    float4 yb_ = *(const float4*)(X + (size_t)rm1 * 128 + kk * 32 + quad * 8 + 4);
    v0[kk][0]=xa.x; v0[kk][1]=xa.y; v0[kk][2]=xa.z; v0[kk][3]=xa.w;
    v0[kk][4]=xb.x; v0[kk][5]=xb.y; v0[kk][6]=xb.z; v0[kk][7]=xb.w;
    v1[kk][0]=ya.x; v1[kk][1]=ya.y; v1[kk][2]=ya.z; v1[kk][3]=ya.w;
    v1[kk][4]=yb_.x; v1[kk][5]=yb_.y; v1[kk][6]=yb_.z; v1[kk][7]=yb_.w;
    #pragma unroll
    for (int j = 0; j < 8; ++j){
      s0 += v0[kk][j]; ss0 += v0[kk][j] * v0[kk][j];
      s1 += v1[kk][j]; ss1 += v1[kk][j] * v1[kk][j];
    }
  }
  s0 += __shfl_xor(s0, 16, 64); ss0 += __shfl_xor(ss0, 16, 64);
  s0 += __shfl_xor(s0, 32, 64); ss0 += __shfl_xor(ss0, 32, 64);
  s1 += __shfl_xor(s1, 16, 64); ss1 += __shfl_xor(ss1, 16, 64);
  s1 += __shfl_xor(s1, 32, 64); ss1 += __shfl_xor(ss1, 32, 64);
  float mu0 = s0 * (1.0f/128.0f), var0 = ss0 * (1.0f/128.0f) - mu0*mu0;
  float mu1 = s1 * (1.0f/128.0f), var1 = ss1 * (1.0f/128.0f) - mu1*mu1;
  float rs0 = rsqrtf(var0 + 1e-5f), rs1 = rsqrtf(var1 + 1e-5f);

  short8 a0[4], a1[4];
  #pragma unroll
  for (int kk = 0; kk < 4; ++kk){
    float4 ga = *(const float4*)(g  + kk * 32 + quad * 8);
    float4 gb = *(const float4*)(g  + kk * 32 + quad * 8 + 4);
    float4 ba = *(const float4*)(bt + kk * 32 + quad * 8);
    float4 bb = *(const float4*)(bt + kk * 32 + quad * 8 + 4);
    float gg[8] = {ga.x,ga.y,ga.z,ga.w,gb.x,gb.y,gb.z,gb.w};
    float bbv[8] = {ba.x,ba.y,ba.z,ba.w,bb.x,bb.y,bb.z,bb.w};
    #pragma unroll
    for (int j = 0; j < 8; ++j){
      float h0 = fmaxf((v0[kk][j] - mu0) * rs0 * gg[j] + bbv[j], 0.0f);
      float h1 = fmaxf((v1[kk][j] - mu1) * rs1 * gg[j] + bbv[j], 0.0f);
      a0[kk][j] = (short)f2bf(h0);
      a1[kk][j] = (short)f2bf(h1);
    }
  }

  f32x4 acc[2][8];
  #pragma unroll
  for (int mt = 0; mt < 2; ++mt)
    #pragma unroll
    for (int nt = 0; nt < 8; ++nt) acc[mt][nt] = (f32x4){0.f, 0.f, 0.f, 0.f};
  __syncthreads();
  #pragma unroll
  for (int kk = 0; kk < 4; ++kk){
    #pragma unroll
    for (int nt = 0; nt < 8; ++nt){
      short8 b = *(const short8*)&ldsb[(nt * 16 + l15) * 136 + kk * 32 + quad * 8];
      acc[0][nt] = __builtin_amdgcn_mfma_f32_16x16x32_bf16(a0[kk], b, acc[0][nt], 0, 0, 0);
      acc[1][nt] = __builtin_amdgcn_mfma_f32_16x16x32_bf16(a1[kk], b, acc[1][nt], 0, 0, 0);
    }
  }
  #pragma unroll
  for (int mt = 0; mt < 2; ++mt)
    #pragma unroll
    for (int nt = 0; nt < 8; ++nt)
      #pragma unroll
      for (int r = 0; r < 4; ++r){
        int row = rowbase + mt * 16 + quad * 4 + r;
        if (row < N_NODES)
          Y[(size_t)row * 128 + nt * 16 + l15] = (unsigned short)f2bf(acc[mt][nt][r]);
      }
}

// ---------------- MFMA GEMM on bf16 input (layers 1,2) ----------------

__global__ __launch_bounds__(256) void gemm_mfma(const unsigned short* __restrict__ A,
                                                 const unsigned short* __restrict__ Wt,
                                                 unsigned short* __restrict__ Y){
  __shared__ unsigned short ldsb[128 * 136];
  int tid = threadIdx.x;
  #pragma unroll
  for (int it = 0; it < 8; ++it){
    int c  = tid + it * 256;
    int n  = c >> 4, kc = c & 15;
    *(short8*)&ldsb[n * 136 + kc * 8] = *(const short8*)(Wt + n * 128 + kc * 8);
  }
  int wave = tid >> 6, lane = tid & 63, quad = lane >> 4, l15 = lane & 15;
  int rowbase = blockIdx.x * 128 + wave * 32;
  int rm0 = rowbase + l15;      if (rm0 > N_NODES - 1) rm0 = N_NODES - 1;
  int rm1 = rowbase + 16 + l15; if (rm1 > N_NODES - 1) rm1 = N_NODES - 1;

  short8 a0[4], a1[4];
  #pragma unroll
  for (int kk = 0; kk < 4; ++kk){
    a0[kk] = *(const short8*)(A + (size_t)rm0 * 128 + kk * 32 + quad * 8);
    a1[kk] = *(const short8*)(A + (size_t)rm1 * 128 + kk * 32 + quad * 8);
  }
  f32x4 acc[2][8];
  #pragma unroll
  for (int mt = 0; mt < 2; ++mt)
    #pragma unroll
    for (int nt = 0; nt < 8; ++nt) acc[mt][nt] = (f32x4){0.f, 0.f, 0.f, 0.f};
  __syncthreads();
  #pragma unroll
  for (int kk = 0; kk < 4; ++kk){
    #pragma unroll
    for (int nt = 0; nt < 8; ++nt){
      short8 b = *(const short8*)&ldsb[(nt * 16 + l15) * 136 + kk * 32 + quad * 8];
      acc[0][nt] = __builtin_amdgcn_mfma_f32_16x16x32_bf16(a0[kk], b, acc[0][nt], 0, 0, 0);
      acc[1][nt] = __builtin_amdgcn_mfma_f32_16x16x32_bf16(a1[kk], b, acc[1][nt], 0, 0, 0);
    }
  }
  #pragma unroll
  for (int mt = 0; mt < 2; ++mt)
    #pragma unroll
    for (int nt = 0; nt < 8; ++nt)
      #pragma unroll
      for (int r = 0; r < 4; ++r){
        int row = rowbase + mt * 16 + quad * 4 + r;
        if (row < N_NODES)
          Y[(size_t)row * 128 + nt * 16 + l15] = (unsigned short)f2bf(acc[mt][nt][r]);
      }
}

// ---------------- Aggregate: 4 nodes/wave, uint4 gathers, packed 4-B ELL ----------------
// Wave = 4 groups of 16 lanes; group g -> node wave*4+g; lane hl holds feats [hl*8, hl*8+8).
// ELL row (64 x 4 B) preloaded into 4 uint regs; one __shfl yields packed (src,w).

template<bool HAS_RES, bool DO_LN>
__global__ __launch_bounds__(256) void agg_kernel(const unsigned short* __restrict__ y,
                                                  const int* __restrict__ cnt,
                                                  const unsigned int* __restrict__ ell,
                                                  const float* __restrict__ bias,
                                                  const float* __restrict__ res,
                                                  float* __restrict__ outp,
                                                  const float* __restrict__ lng,
                                                  const float* __restrict__ lnb,
                                                  unsigned short* __restrict__ hn_out){
  int wv   = (blockIdx.x * 256 + threadIdx.x) >> 6;  // 12500 waves exactly (50000/4)
  int lane = threadIdx.x & 63;
  int hl   = lane & 15;
  int node = wv * 4 + (lane >> 4);
  int selbase = lane & 48;
  const uint4* y4 = (const uint4*)y;                 // row = 16 uint4

  int deg = cnt[node];
  float di = rsqrtf((float)(deg + 1));
  float ws = di * di;                                // self-loop weight

  const unsigned int* row = ell + (size_t)node * ELLW;
  unsigned int e0 = row[hl], e1 = row[hl + 16], e2 = row[hl + 32], e3 = row[hl + 48];

  int J = deg;
  J = max(J, __shfl_xor(J, 16, 64));
  J = max(J, __shfl_xor(J, 32, 64));

  uint4 us = y4[(size_t)node * 16 + hl];
  float acc0 = ws * bflo(us.x), acc1 = ws * bfhi(us.x);
  float acc2 = ws * bflo(us.y), acc3 = ws * bfhi(us.y);
  float acc4 = ws * bflo(us.z), acc5 = ws * bfhi(us.z);
  float acc6 = ws * bflo(us.w), acc7 = ws * bfhi(us.w);

  auto block16 = [&](unsigned int ee, int base16){
    int rem = J - base16;
    if (rem <= 0) return;
    int nch = (min(rem, 16) + 3) >> 2;               // wave-uniform chunk count
    for (int c = 0; c < nch; ++c){
      int rb = c * 4;
      unsigned int pA = (unsigned)__shfl((int)ee, selbase | (rb + 0), 64);
      unsigned int pB = (unsigned)__shfl((int)ee, selbase | (rb + 1), 64);
      unsigned int pC = (unsigned)__shfl((int)ee, selbase | (rb + 2), 64);
      unsigned int pD = (unsigned)__shfl((int)ee, selbase | (rb + 3), 64);
      uint4 gA = y4[(size_t)(pA & 0xFFFFu) * 16 + hl];
      uint4 gB = y4[(size_t)(pB & 0xFFFFu) * 16 + hl];
      uint4 gC = y4[(size_t)(pC & 0xFFFFu) * 16 + hl];
      uint4 gD = y4[(size_t)(pD & 0xFFFFu) * 16 + hl];
      float wA = bfhi(pA), wB = bfhi(pB), wC = bfhi(pC), wD = bfhi(pD);
      acc0 += wA*bflo(gA.x); acc1 += wA*bfhi(gA.x); acc2 += wA*bflo(gA.y); acc3 += wA*bfhi(gA.y);
      acc4 += wA*bflo(gA.z); acc5 += wA*bfhi(gA.z); acc6 += wA*bflo(gA.w); acc7 += wA*bfhi(gA.w);
      acc0 += wB*bflo(gB.x); acc1 += wB*bfhi(gB.x); acc2 += wB*bflo(gB.y); acc3 += wB*bfhi(gB.y);
      acc4 += wB*bflo(gB.z); acc5 += wB*bfhi(gB.z); acc6 += wB*bflo(gB.w); acc7 += wB*bfhi(gB.w);
      acc0 += wC*bflo(gC.x); acc1 += wC*bfhi(gC.x); acc2 += wC*bflo(gC.y); acc3 += wC*bfhi(gC.y);
      acc4 += wC*bflo(gC.z); acc5 += wC*bfhi(gC.z); acc6 += wC*bflo(gC.w); acc7 += wC*bfhi(gC.w);
      acc0 += wD*bflo(gD.x); acc1 += wD*bfhi(gD.x); acc2 += wD*bflo(gD.y); acc3 += wD*bfhi(gD.y);
      acc4 += wD*bflo(gD.z); acc5 += wD*bfhi(gD.z); acc6 += wD*bflo(gD.w); acc7 += wD*bfhi(gD.w);
    }
  };
  block16(e0, 0); block16(e1, 16); block16(e2, 32); block16(e3, 48);

  float4 ubA = ((const float4*)bias)[hl * 2];
  float4 ubB = ((const float4*)bias)[hl * 2 + 1];
  acc0 += ubA.x; acc1 += ubA.y; acc2 += ubA.z; acc3 += ubA.w;
  acc4 += ubB.x; acc5 += ubB.y; acc6 += ubB.z; acc7 += ubB.w;
  if (HAS_RES){
    float4 urA = ((const float4*)res)[(size_t)node * 32 + hl * 2];
    float4 urB = ((const float4*)res)[(size_t)node * 32 + hl * 2 + 1];
    acc0 += urA.x; acc1 += urA.y; acc2 += urA.z; acc3 += urA.w;
    acc4 += urB.x; acc5 += urB.y; acc6 += urB.z; acc7 += urB.w;
  }
  if (outp){
    float4 oA; oA.x = acc0; oA.y = acc1; oA.z = acc2; oA.w = acc3;
    float4 oB; oB.x = acc4; oB.y = acc5; oB.z = acc6; oB.w = acc7;
    ((float4*)outp)[(size_t)node * 32 + hl * 2]     = oA;
    ((float4*)outp)[(size_t)node * 32 + hl * 2 + 1] = oB;
  }

  if (DO_LN){
    float s  = acc0 + acc1 + acc2 + acc3 + acc4 + acc5 + acc6 + acc7;
    float ss = acc0*acc0 + acc1*acc1 + acc2*acc2 + acc3*acc3
             + acc4*acc4 + acc5*acc5 + acc6*acc6 + acc7*acc7;
    #pragma unroll
    for (int d = 8; d >= 1; d >>= 1){ s += __shfl_xor(s, d, 64); ss += __shfl_xor(ss, d, 64); }
    float mu  = s * (1.0f / 128.0f);
    float var = ss * (1.0f / 128.0f) - mu * mu;
    float rs  = rsqrtf(var + 1e-5f);
    float4 ugA = ((const float4*)lng)[hl * 2];
    float4 ugB = ((const float4*)lng)[hl * 2 + 1];
    float4 ubbA = ((const float4*)lnb)[hl * 2];
    float4 ubbB = ((const float4*)lnb)[hl * 2 + 1];
    float h0 = fmaxf((acc0 - mu) * rs * ugA.x + ubbA.x, 0.0f);
    float h1 = fmaxf((acc1 - mu) * rs * ugA.y + ubbA.y, 0.0f);
    float h2 = fmaxf((acc2 - mu) * rs * ugA.z + ubbA.z, 0.0f);
    float h3 = fmaxf((acc3 - mu) * rs * ugA.w + ubbA.w, 0.0f);
    float h4 = fmaxf((acc4 - mu) * rs * ugB.x + ubbB.x, 0.0f);
    float h5 = fmaxf((acc5 - mu) * rs * ugB.y + ubbB.y, 0.0f);
    float h6 = fmaxf((acc6 - mu) * rs * ugB.z + ubbB.z, 0.0f);
    float h7 = fmaxf((acc7 - mu) * rs * ugB.w + ubbB.w, 0.0f);
    uint4 ho;
    ho.x = pack2(h0, h1); ho.y = pack2(h2, h3);
    ho.z = pack2(h4, h5); ho.w = pack2(h6, h7);
    ((uint4*)hn_out)[(size_t)node * 16 + hl] = ho;
  }
}

// ---------------- launch ----------------

extern "C" void kernel_launch(void* const* d_in, const int* in_sizes, int n_in,
                              void* d_out, int out_size, void* d_ws, size_t ws_size,
                              hipStream_t stream){
  const float* x    = (const float*)d_in[0];
  const int*   edges= (const int*)d_in[1];
  const float* lng0 = (const float*)d_in[2];
  const float* lnb0 = (const float*)d_in[3];
  const float* W0   = (const float*)d_in[4];
  const float* b0   = (const float*)d_in[5];
  const float* lng1 = (const float*)d_in[6];
  const float* lnb1 = (const float*)d_in[7];
  const float* W1   = (const float*)d_in[8];
  const float* b1   = (const float*)d_in[9];
  const float* lng2 = (const float*)d_in[10];
  const float* lnb2 = (const float*)d_in[11];
  const float* W2   = (const float*)d_in[12];
  const float* b2   = (const float*)d_in[13];

  char* p = (char*)d_ws;
  auto carve = [&](size_t bytes) -> void* {
    void* r = (void*)p;
    p += (bytes + 255) & ~(size_t)255;
    return r;
  };
  int*          cnt  = (int*)         carve(N_NODES * 4);
  int*          epos = (int*)         carve((size_t)E_EDGES * 4);
  unsigned int* ell  = (unsigned int*)carve((size_t)N_NODES * ELLW * 4);   // 12.8 MB packed
  unsigned short* Wt = (unsigned short*)carve(3 * 128 * 128 * 2);
  unsigned short* hn = (unsigned short*)carve((size_t)N_NODES * 128 * 2);
  unsigned short* yb = (unsigned short*)carve((size_t)N_NODES * 128 * 2);
  float* out = (float*)d_out;   // doubles as x1 storage (layer-0 residual output)

  hipMemsetAsync(cnt, 0, N_NODES * 4, stream);   // 200 KB only

  count_kernel<<<(E_EDGES + 255) / 256, 256, 0, stream>>>(edges, cnt, epos);
  prep_kernel<<<3513, 256, 0, stream>>>(edges, epos, cnt, ell, W0, W1, W2, Wt);

  const int GEMM_GRID = (N_NODES + 127) / 128;      // 391
  const int AGG_GRID  = N_NODES / 4 / 4;            // 3125 blocks = 12500 waves, exact

  // layer 0: y = relu(LN0(x))@W0 (fused) ; x1 = agg(y)+b0+x -> d_out ; fused LN1 -> hn
  gemm_ln_mfma<<<GEMM_GRID, 256, 0, stream>>>(x, lng0, lnb0, Wt, yb);
  agg_kernel<true, true><<<AGG_GRID, 256, 0, stream>>>(yb, cnt, ell,
                                                       b0, x, out, lng1, lnb1, hn);
  // layer 1: y = hn@W1 ; h1 = agg(y)+b1 (not materialized) ; fused LN2(h1) -> hn
  gemm_mfma<<<GEMM_GRID, 256, 0, stream>>>(hn, Wt + 16384, yb);
  agg_kernel<false, true><<<AGG_GRID, 256, 0, stream>>>(yb, cnt, ell,
                                                        b1, nullptr, nullptr, lng2, lnb2, hn);
  // layer 2: y = hn@W2 ; out = agg(y)+b2+x1  (x1 read from d_out, overwritten in place)
  gemm_mfma<<<GEMM_GRID, 256, 0, stream>>>(hn, Wt + 32768, yb);
  agg_kernel<true, false><<<AGG_GRID, 256, 0, stream>>>(yb, cnt, ell,
                                                        b2, out, out, nullptr, nullptr, nullptr);
}